// Round 1
// baseline (6473.017 us; speedup 1.0000x reference)
//
#include <hip/hip_runtime.h>

// Per-channel LSTM (input_size=1) + per-channel Linear(H,1), fully fused.
// B=512, T=1024, C=64, H=128. One workgroup = (channel, 128-row batch tile).
// W_hh fragments live in registers (64 VGPR/lane); h ping-pongs through LDS
// in MFMA-A-fragment swizzled layout; one barrier per timestep.

typedef _Float16 half8 __attribute__((ext_vector_type(8)));
typedef float floatx4 __attribute__((ext_vector_type(4)));

#define LOG2E 1.44269504088896340736f

__global__ __launch_bounds__(512, 2) void lstm_fused(
    const float* __restrict__ x,    // [B,T,C]
    const float* __restrict__ Wih,  // [C,4H]
    const float* __restrict__ Whh,  // [C,4H,H]
    const float* __restrict__ bih,  // [C,4H]
    const float* __restrict__ bhh,  // [C,4H]
    const float* __restrict__ Wfc,  // [C,H]
    const float* __restrict__ bfc,  // [C]
    float* __restrict__ out)        // [B,C]
{
    constexpr int T = 1024, C = 64, H = 128, G = 512;
    constexpr int TC = T * C;

    // Two h buffers, each [8 rowtiles][4 ksteps][64 lanes][8 f16] = 32 KB.
    __shared__ _Float16 hbuf[2][16384];

    const int bid = blockIdx.x;
    const int ch  = bid >> 2;        // channel 0..63
    const int b0  = (bid & 3) << 7;  // batch tile base: 0,128,256,384

    const int tid = threadIdx.x;
    const int w   = tid >> 6;        // wave 0..7 -> owns hidden slice [w*16, w*16+16)
    const int l   = tid & 63;
    const int q   = l >> 4;          // quad
    const int li  = l & 15;

    // ---- load per-lane constants: W_ih, bias, W_hh fragments (registers) ----
    // wave w, gate ct: column = ct*H + w*16 + li ; B-frag: B[n=li][k=q*8+j]
    float wihr[4], bias[4];
    half8 Wf[4][4];
#pragma unroll
    for (int ct = 0; ct < 4; ++ct) {
        const float sc = (ct == 2) ? 2.0f * LOG2E : LOG2E;  // gate order i,f,g,o
        const int col = ct * H + w * 16 + li;
        wihr[ct] = Wih[ch * G + col] * sc;
        bias[ct] = (bih[ch * G + col] + bhh[ch * G + col]) * sc;
#pragma unroll
        for (int ks = 0; ks < 4; ++ks) {
            const float* wp = &Whh[((size_t)(ch * G + col)) * H + ks * 32 + q * 8];
            half8 hv;
#pragma unroll
            for (int j = 0; j < 8; ++j) hv[j] = (_Float16)(wp[j] * sc);
            Wf[ct][ks] = hv;
        }
    }

    // zero the t=0 read buffer (h0 = 0)
    for (int i = tid; i < 16384; i += 512) hbuf[0][i] = (_Float16)0.0f;

    // cell state (fp32, registers): 8 rowtiles x 4 rows
    float cst[8][4];
#pragma unroll
    for (int rt = 0; rt < 8; ++rt)
#pragma unroll
        for (int r = 0; r < 4; ++r) cst[rt][r] = 0.0f;

    // h write swizzle (A-frag layout of the NEXT step's reads):
    // element (row, hh): rt=row>>4, m=row&15, ks=hh>>5, qq=(hh&31)>>3, j=hh&7
    // offset = ((rt*4+ks)*64 + qq*16 + m)*8 + j
    const int ks_w = w >> 1;
    const int qq_w = ((w & 1) << 1) + (li >> 3);
    const int j_w  = li & 7;

    const float* xb = x + (size_t)b0 * TC + ch;  // + row*TC + t*C

    // x prefetch registers
    float xv[8][4], xn[8][4];
#pragma unroll
    for (int rt = 0; rt < 8; ++rt)
#pragma unroll
        for (int r = 0; r < 4; ++r)
            xv[rt][r] = xb[(size_t)(rt * 16 + q * 4 + r) * TC];  // t = 0

    __syncthreads();

    for (int t = 0; t < T; ++t) {
        const _Float16* rb = hbuf[t & 1];
        _Float16* wb = hbuf[(t & 1) ^ 1];

        // prefetch x for t+1 (wrap at T to stay in-bounds; value unused at t=T-1)
        const int tn = (t + 1) & (T - 1);
#pragma unroll
        for (int rt = 0; rt < 8; ++rt)
#pragma unroll
            for (int r = 0; r < 4; ++r)
                xn[rt][r] = xb[(size_t)(rt * 16 + q * 4 + r) * TC + (size_t)tn * C];

        const bool last = (t == T - 1);

#pragma unroll
        for (int rt = 0; rt < 8; ++rt) {
            // init acc with x*W_ih + b (pre-scaled)
            floatx4 acc[4];
#pragma unroll
            for (int ct = 0; ct < 4; ++ct)
#pragma unroll
                for (int r = 0; r < 4; ++r)
                    acc[ct][r] = fmaf(xv[rt][r], wihr[ct], bias[ct]);

            // A fragments of previous h for this rowtile (conflict-free b128)
            const half8 a0 = *(const half8*)&rb[(rt * 4 + 0) * 512 + l * 8];
            const half8 a1 = *(const half8*)&rb[(rt * 4 + 1) * 512 + l * 8];
            const half8 a2 = *(const half8*)&rb[(rt * 4 + 2) * 512 + l * 8];
            const half8 a3 = *(const half8*)&rb[(rt * 4 + 3) * 512 + l * 8];

#pragma unroll
            for (int ct = 0; ct < 4; ++ct) {
                acc[ct] = __builtin_amdgcn_mfma_f32_16x16x32_f16(a0, Wf[ct][0], acc[ct], 0, 0, 0);
                acc[ct] = __builtin_amdgcn_mfma_f32_16x16x32_f16(a1, Wf[ct][1], acc[ct], 0, 0, 0);
                acc[ct] = __builtin_amdgcn_mfma_f32_16x16x32_f16(a2, Wf[ct][2], acc[ct], 0, 0, 0);
                acc[ct] = __builtin_amdgcn_mfma_f32_16x16x32_f16(a3, Wf[ct][3], acc[ct], 0, 0, 0);
            }

            // activations + state update + h write (gates pre-scaled by log2e)
#pragma unroll
            for (int r = 0; r < 4; ++r) {
                const float ig = __builtin_amdgcn_rcpf(1.0f + __builtin_amdgcn_exp2f(-acc[0][r]));
                const float fg = __builtin_amdgcn_rcpf(1.0f + __builtin_amdgcn_exp2f(-acc[1][r]));
                const float gg = 1.0f - 2.0f * __builtin_amdgcn_rcpf(1.0f + __builtin_amdgcn_exp2f(acc[2][r]));
                const float og = __builtin_amdgcn_rcpf(1.0f + __builtin_amdgcn_exp2f(-acc[3][r]));
                const float cn = fg * cst[rt][r] + ig * gg;
                cst[rt][r] = cn;
                const float tc = 1.0f - 2.0f * __builtin_amdgcn_rcpf(
                                     1.0f + __builtin_amdgcn_exp2f(cn * (2.0f * LOG2E)));
                const float hv = og * tc;
                wb[((rt * 4 + ks_w) * 64 + qq_w * 16 + q * 4 + r) * 8 + j_w] = (_Float16)hv;
                (void)last;
            }
        }

        // rotate x prefetch
#pragma unroll
        for (int rt = 0; rt < 8; ++rt)
#pragma unroll
            for (int r = 0; r < 4; ++r) xv[rt][r] = xn[rt][r];

        __syncthreads();  // wb complete before next step reads it
    }

    // ---- epilogue: out[b0+row, ch] = sum_hh h_final[row][hh]*Wfc[ch][hh] + bfc ----
    // Final h (t=1023 wrote buffer 0) is in hbuf[0], swizzled layout.
    if (tid < 128) {
        const int row = tid;
        const int rt = row >> 4, m = row & 15;
        float s = bfc[ch];
#pragma unroll
        for (int hh = 0; hh < H; ++hh) {
            const int ks = hh >> 5, qq = (hh & 31) >> 3, j = hh & 7;
            s += (float)hbuf[0][((rt * 4 + ks) * 64 + qq * 16 + m) * 8 + j] * Wfc[ch * H + hh];
        }
        out[(size_t)(b0 + row) * C + ch] = s;
    }
}

extern "C" void kernel_launch(void* const* d_in, const int* in_sizes, int n_in,
                              void* d_out, int out_size, void* d_ws, size_t ws_size,
                              hipStream_t stream) {
    const float* x   = (const float*)d_in[0];
    const float* Wih = (const float*)d_in[1];
    const float* Whh = (const float*)d_in[2];
    const float* bih = (const float*)d_in[3];
    const float* bhh = (const float*)d_in[4];
    const float* Wfc = (const float*)d_in[5];
    const float* bfc = (const float*)d_in[6];
    float* out = (float*)d_out;

    lstm_fused<<<256, 512, 0, stream>>>(x, Wih, Whh, bih, bhh, Wfc, bfc, out);
}